// Round 1
// baseline (76.820 us; speedup 1.0000x reference)
//
#include <hip/hip_runtime.h>

// Problem constants (fixed by setup_inputs)
#define T_DIM 32
#define B_DIM 64
#define D_DIM 256
#define P_DIM 1024
#define NK    17
#define DT    0.1875f    // 3/16
#define DT_REV 0.029841551329651566f   // DT / (2*pi) -- v_sin/v_cos take revolutions

typedef __bf16 bf16x8 __attribute__((ext_vector_type(8)));
typedef float  f32x16 __attribute__((ext_vector_type(16)));

static __device__ __forceinline__ unsigned f2bf(float f) {
  unsigned u = __float_as_uint(f);
  u += 0x7fffu + ((u >> 16) & 1u);     // round-to-nearest-even
  return u >> 16;
}

// ---------------------------------------------------------------------------
// Workspace layout (d_ws, poisoned by harness each call -- we fully rewrite):
//   abt   @ 0        : [P][D] bf16  A transposed, UNNORMALIZED   (512 KB)
//   projb @ 512 KB   : [T][B][D] bf16                            (1 MB)
//   invn  @ 1536 KB  : [P] f32  1/clamp_min(colnorm)             (4 KB)
// ---------------------------------------------------------------------------

// Prep: one launch, 160 blocks.
//   blocks 0..31  : A -> abt (transpose + bf16) + column sq-norms -> invn
//   blocks 32..159: proj -> projb (bf16), 65536 x 16B groups, 2 per thread
__global__ __launch_bounds__(256) void prep_kernel(const float* __restrict__ proj,
                                                   const float* __restrict__ A,
                                                   unsigned short* __restrict__ abt,
                                                   unsigned short* __restrict__ projb,
                                                   float* __restrict__ invn) {
  const int bid = blockIdx.x;
  const int tid = threadIdx.x;
  if (bid < 32) {
    __shared__ float red[8][32];
    const int c  = tid & 31;
    const int rg = tid >> 5;             // 8 row-groups of 32 rows
    const int p  = bid * 32 + c;
    float v[32];
#pragma unroll
    for (int i = 0; i < 32; ++i) v[i] = A[(size_t)(rg * 32 + i) * P_DIM + p];
    float s = 0.f;
#pragma unroll
    for (int i = 0; i < 32; ++i) s = fmaf(v[i], v[i], s);
    red[rg][c] = s;
    // transpose + convert this thread's 32 rows of column p
#pragma unroll
    for (int i = 0; i < 4; ++i) {
      uint4 w;
      w.x = f2bf(v[i * 8 + 0]) | (f2bf(v[i * 8 + 1]) << 16);
      w.y = f2bf(v[i * 8 + 2]) | (f2bf(v[i * 8 + 3]) << 16);
      w.z = f2bf(v[i * 8 + 4]) | (f2bf(v[i * 8 + 5]) << 16);
      w.w = f2bf(v[i * 8 + 6]) | (f2bf(v[i * 8 + 7]) << 16);
      *(uint4*)&abt[p * D_DIM + rg * 32 + i * 8] = w;
    }
    __syncthreads();
    if (tid < 32) {
      float t = 0.f;
#pragma unroll
      for (int g = 0; g < 8; ++g) t += red[g][tid];
      invn[bid * 32 + tid] = rsqrtf(fmaxf(t, 1e-24f));  // 1/clamp_min(norm,1e-12)
    }
  } else {
    // proj: 524288 floats = 65536 groups of 8; 128 blocks * 256 thr = 32768
    const float4* Pg = (const float4*)proj;
    uint4* Pb = (uint4*)projb;
    int g = (bid - 32) * 256 + tid;
#pragma unroll
    for (int r = 0; r < 2; ++r, g += 32768) {
      float4 v0 = Pg[2 * g], v1 = Pg[2 * g + 1];
      uint4 w;
      w.x = f2bf(v0.x) | (f2bf(v0.y) << 16);
      w.y = f2bf(v0.z) | (f2bf(v0.w) << 16);
      w.z = f2bf(v1.x) | (f2bf(v1.y) << 16);
      w.w = f2bf(v1.z) | (f2bf(v1.w) << 16);
      Pb[g] = w;
    }
  }
}

// ---------------------------------------------------------------------------
// Main: grid (16 ptile, 32 t) x 256 thr (4 waves). No LDS staging: MFMA frags
// read straight from the preconverted bf16 buffers (1.5 MB total -- L2-hot).
// Each wave owns one 32x32 output tile (mt = b-half, nt = p-half), full K=256
// in 16 MFMA steps. Trig/epilogue identical to the proven fused kernel.
// LDS: planes [16 k][128] cos + sin (16 KB) + 4 wave partials.
// ---------------------------------------------------------------------------
__global__ __launch_bounds__(256) void sig_main(const unsigned short* __restrict__ projb,
                                                const unsigned short* __restrict__ abt,
                                                const float* __restrict__ invn,
                                                float* __restrict__ out) {
  __shared__ float smf[4100];

  const int tid  = threadIdx.x;
  const int lane = tid & 63;
  const int wv   = tid >> 6;                     // 0..3
  const int p0   = blockIdx.x * 64;
  const int t    = blockIdx.y;

  const int mt  = wv >> 1, nt = wv & 1;
  const int l31 = lane & 31;
  const int hi  = lane >> 5;                     // k-sub half

  // A-operand frag: proj[t][mt*32 + l31][k]; B-operand frag: A^T[p][k]
  const unsigned short* ap = projb + ((size_t)t * B_DIM + mt * 32 + l31) * D_DIM + hi * 8;
  const unsigned short* bp = abt + (size_t)(p0 + nt * 32 + l31) * D_DIM + hi * 8;

  f32x16 acc = {0.f, 0.f, 0.f, 0.f, 0.f, 0.f, 0.f, 0.f,
                0.f, 0.f, 0.f, 0.f, 0.f, 0.f, 0.f, 0.f};
#pragma unroll
  for (int ks = 0; ks < 16; ++ks) {              // K = 16 steps x 16
    bf16x8 af = *(const bf16x8*)(ap + ks * 16);
    bf16x8 bf = *(const bf16x8*)(bp + ks * 16);
    acc = __builtin_amdgcn_mfma_f32_32x32x16_bf16(af, bf, acc, 0, 0, 0);
  }
  // acc reg r = x_unnorm[b = mt*32+(r&3)+8*(r>>2)+4*hi][p = nt*32+l31]

  // scale to REVOLUTIONS: theta = x*invnorm*DT, hw trig wants theta/2pi
  const float invdt = invn[p0 + nt * 32 + l31] * DT_REV;

  // ---- Chebyshev trig via HW v_sin/v_cos: sums over this lane's 16 b's ----
  float cs[NK - 1], ss[NK - 1];
#pragma unroll
  for (int k = 0; k < NK - 1; ++k) { cs[k] = 0.f; ss[k] = 0.f; }
#pragma unroll
  for (int r = 0; r < 16; ++r) {
    float th = acc[r] * invdt;                   // revolutions, |th| << 1
    float c1 = __builtin_amdgcn_cosf(th);        // v_cos_f32: cos(2*pi*th)
    float s1 = __builtin_amdgcn_sinf(th);        // v_sin_f32: sin(2*pi*th)
    float twoc = 2.f * c1;
    float ckm1 = 1.f, skm1 = 0.f;
    float ck = c1, sk = s1;
    cs[0] += c1;
    ss[0] += s1;
#pragma unroll
    for (int k = 2; k < NK; ++k) {
      float cn = fmaf(twoc, ck, -ckm1);
      float sn = fmaf(twoc, sk, -skm1);
      cs[k - 1] += cn;
      ss[k - 1] += sn;
      ckm1 = ck; skm1 = sk; ck = cn; sk = sn;
    }
  }

  // ---- combine the two b-halves (lane L and L^32 share the same p col) ----
#pragma unroll
  for (int k = 0; k < NK - 1; ++k) {
    cs[k] += __shfl_xor(cs[k], 32, 64);
    ss[k] += __shfl_xor(ss[k], 32, 64);
  }

  // ---- planes: cos[16][2 mt][64 p] @0, sin @2048 ----
  if (lane < 32) {
    int p = nt * 32 + l31;
#pragma unroll
    for (int k = 0; k < NK - 1; ++k) {
      smf[k * 128 + mt * 64 + p]        = cs[k];
      smf[2048 + k * 128 + mt * 64 + p] = ss[k];
    }
  }
  __syncthreads();

  // ---- per-(k,p) error + weight dot ----
  float part = 0.f;
#pragma unroll
  for (int r = 0; r < 4; ++r) {
    int e  = tid + r * 256;                      // 0..1023
    int k1 = e >> 6;
    int pl = e & 63;
    float C = smf[k1 * 128 + pl] + smf[k1 * 128 + 64 + pl];
    float S = smf[2048 + k1 * 128 + pl] + smf[2048 + k1 * 128 + 64 + pl];
    float cm  = C * (1.f / 64.f);
    float sm_ = S * (1.f / 64.f);
    float tk  = (float)(k1 + 1) * DT;
    float phi = __expf(-0.5f * tk * tk);
    float wk  = ((k1 == NK - 2) ? DT : 2.f * DT) * phi;   // k=16 endpoint
    float dc  = cm - phi;
    part = fmaf(wk, fmaf(dc, dc, sm_ * sm_), part);
  }
  part *= (1.f / 512.f);                         // * B / (T*P)

  // ---- block reduce -> one atomic per block ----
#pragma unroll
  for (int off = 32; off > 0; off >>= 1)
    part += __shfl_down(part, off, 64);
  __syncthreads();                               // done reading planes
  if (lane == 0) smf[4096 + wv] = part;
  __syncthreads();
  if (tid == 0)
    atomicAdd(out, smf[4096] + smf[4097] + smf[4098] + smf[4099]);
}

// ---------------------------------------------------------------------------
extern "C" void kernel_launch(void* const* d_in, const int* in_sizes, int n_in,
                              void* d_out, int out_size, void* d_ws, size_t ws_size,
                              hipStream_t stream) {
  const float* proj = (const float*)d_in[0];     // (32,64,256) fp32
  const float* A    = (const float*)d_in[1];     // (256,1024) fp32
  float* out        = (float*)d_out;             // 1 fp32 scalar

  unsigned short* abt   = (unsigned short*)d_ws;                        // 512 KB
  unsigned short* projb = (unsigned short*)((char*)d_ws + (512 << 10)); // 1 MB
  float*          invn  = (float*)((char*)d_ws + (1536 << 10));         // 4 KB

  hipMemsetAsync(out, 0, sizeof(float), stream); // d_out poisoned each call
  prep_kernel<<<160, 256, 0, stream>>>(proj, A, abt, projb, invn);
  sig_main<<<dim3(16, 32), dim3(256), 0, stream>>>(projb, abt, invn, out);
}

// Round 2
// 71.860 us; speedup vs baseline: 1.0690x; 1.0690x over previous
//
#include <hip/hip_runtime.h>

// Problem constants (fixed by setup_inputs)
#define T_DIM 32
#define B_DIM 64
#define D_DIM 256
#define P_DIM 1024
#define NK    17
#define DT    0.1875f    // 3/16
#define DT_REV 0.029841551329651566f   // DT / (2*pi) -- v_sin/v_cos take revolutions

#define LROWA 264        // padded A^T row in bf16 (256+8): 132 dwords ≡ 4 (mod 32)
                         //  -> 2-way (free) bank aliasing on ds_read_b128

typedef __bf16 bf16x8 __attribute__((ext_vector_type(8)));
typedef float  f32x16 __attribute__((ext_vector_type(16)));

static __device__ __forceinline__ unsigned f2bf(float f) {
  unsigned u = __float_as_uint(f);
  u += 0x7fffu + ((u >> 16) & 1u);     // round-to-nearest-even
  return u >> 16;
}

// ---------------------------------------------------------------------------
// Single fused kernel. grid (16 ptile, 32 t) x 256 thr (4 waves).
//  - proj MFMA fragments loaded global->register directly (rows are
//    K-contiguous; no transpose needed), fp32->bf16 in-register. Loads are
//    issued BEFORE the A-stage so HBM/L2 latency hides under it.
//  - A staged once for the FULL K=256 into LDS transposed [p][k] bf16
//    (it needs the transpose); column sq-norm partials accumulated during
//    staging, reduced to invn after the stage barrier (norm applied to acc
//    AFTER the GEMM -- it's linear).
//  - 16 back-to-back 32x32x16 bf16 MFMAs, one 32x32 tile per wave.
//  - HW trig (v_sin/v_cos, revolutions) + Chebyshev recurrence; epilogue and
//    one atomicAdd per block identical to the proven kernel.
// Barriers: 4 total (was 6). LDS regions disjoint (no reuse hazards):
//   sa [64][264] bf16 = 33792 B | normred [16][64] | invn [64]
//   planes cos/sin [16][128]x2  | parts [4]        = 54544 B total
// ---------------------------------------------------------------------------
__global__ __launch_bounds__(256) void sig_fused_kernel(const float* __restrict__ proj,
                                                        const float* __restrict__ A,
                                                        float* __restrict__ out) {
  __shared__ float smf[13636];
  unsigned short* sa = (unsigned short*)smf;     // A^T tile [p][k], padded
  float* normred = smf + 8448;                   // [16 kg][64 p]
  float* invn    = smf + 9472;                   // [64]
  float* planes  = smf + 9536;                   // cos [16][128]; sin @ +2048
  float* parts   = smf + 13632;                  // [4]

  const int tid  = threadIdx.x;
  const int lane = tid & 63;
  const int wv   = tid >> 6;                     // 0..3
  const int p0   = blockIdx.x * 64;
  const int t    = blockIdx.y;

  const int mt  = wv >> 1, nt = wv & 1;
  const int l31 = lane & 31;
  const int hi  = lane >> 5;                     // k-sub half

  // ---- proj fragments: direct global->reg, convert to bf16 ----
  // A-operand row of this lane: proj[t][mt*32 + l31][ks*16 + hi*8 .. +8]
  const float* Pr = proj + ((size_t)t * B_DIM + mt * 32 + l31) * D_DIM + hi * 8;
  bf16x8 af[16];
#pragma unroll
  for (int ks = 0; ks < 16; ++ks) {
    float4 u0 = *(const float4*)(Pr + ks * 16);
    float4 u1 = *(const float4*)(Pr + ks * 16 + 4);
    union { bf16x8 v; unsigned u[4]; } w;
    w.u[0] = f2bf(u0.x) | (f2bf(u0.y) << 16);
    w.u[1] = f2bf(u0.z) | (f2bf(u0.w) << 16);
    w.u[2] = f2bf(u1.x) | (f2bf(u1.y) << 16);
    w.u[3] = f2bf(u1.z) | (f2bf(u1.w) << 16);
    af[ks] = w.v;
  }

  // ---- A-stage: full K, transpose + convert + norm partials ----
  // thread owns 4 p-cols (pg) x 16 k's (kg)
  {
    const int pg = tid & 15;                     // p-group (4 p's)
    const int kg = tid >> 4;                     // 0..15, 16 k's each
    const float4* Ag = (const float4*)(A + p0); // row stride P_DIM/4 float4
    float4 va[16];
#pragma unroll
    for (int i = 0; i < 16; ++i)
      va[i] = Ag[(size_t)(kg * 16 + i) * (P_DIM / 4) + pg];
    float nrm[4] = {0.f, 0.f, 0.f, 0.f};
#pragma unroll
    for (int j = 0; j < 4; ++j) {
#pragma unroll
      for (int h = 0; h < 2; ++h) {
        float e0 = ((const float*)&va[h * 8 + 0])[j];
        float e1 = ((const float*)&va[h * 8 + 1])[j];
        float e2 = ((const float*)&va[h * 8 + 2])[j];
        float e3 = ((const float*)&va[h * 8 + 3])[j];
        float e4 = ((const float*)&va[h * 8 + 4])[j];
        float e5 = ((const float*)&va[h * 8 + 5])[j];
        float e6 = ((const float*)&va[h * 8 + 6])[j];
        float e7 = ((const float*)&va[h * 8 + 7])[j];
        nrm[j] = fmaf(e0, e0, nrm[j]); nrm[j] = fmaf(e1, e1, nrm[j]);
        nrm[j] = fmaf(e2, e2, nrm[j]); nrm[j] = fmaf(e3, e3, nrm[j]);
        nrm[j] = fmaf(e4, e4, nrm[j]); nrm[j] = fmaf(e5, e5, nrm[j]);
        nrm[j] = fmaf(e6, e6, nrm[j]); nrm[j] = fmaf(e7, e7, nrm[j]);
        uint4 w;
        w.x = f2bf(e0) | (f2bf(e1) << 16);
        w.y = f2bf(e2) | (f2bf(e3) << 16);
        w.z = f2bf(e4) | (f2bf(e5) << 16);
        w.w = f2bf(e6) | (f2bf(e7) << 16);
        *(uint4*)&sa[(pg * 4 + j) * LROWA + kg * 16 + h * 8] = w;
      }
      normred[kg * 64 + pg * 4 + j] = nrm[j];
    }
  }
  __syncthreads();                               // (1) A tile + normred ready

  // ---- finish column norms -> invn[p] (overlaps other waves' MFMA) ----
  if (tid < 64) {
    float s = 0.f;
#pragma unroll
    for (int q = 0; q < 16; ++q) s += normred[q * 64 + tid];
    invn[tid] = rsqrtf(fmaxf(s, 1e-24f));        // 1/clamp_min(norm, 1e-12)
  }

  // ---- MFMA: 16 k-steps over full K ----
  f32x16 acc = {0.f, 0.f, 0.f, 0.f, 0.f, 0.f, 0.f, 0.f,
                0.f, 0.f, 0.f, 0.f, 0.f, 0.f, 0.f, 0.f};
  const unsigned short* brow = &sa[(nt * 32 + l31) * LROWA + hi * 8];
#pragma unroll
  for (int ks = 0; ks < 16; ++ks) {
    bf16x8 bfr = *(const bf16x8*)(brow + ks * 16);
    acc = __builtin_amdgcn_mfma_f32_32x32x16_bf16(af[ks], bfr, acc, 0, 0, 0);
  }
  // acc reg r = x_unnorm[b = mt*32+(r&3)+8*(r>>2)+4*hi][p = nt*32+l31]
  __syncthreads();                               // (2) invn ready

  // scale to REVOLUTIONS: theta = x*DT, hw trig wants theta/2pi
  const float invdt = invn[nt * 32 + l31] * DT_REV;

  // ---- Chebyshev trig via HW v_sin/v_cos: sums over this lane's 16 b's ----
  float cs[NK - 1], ss[NK - 1];
#pragma unroll
  for (int k = 0; k < NK - 1; ++k) { cs[k] = 0.f; ss[k] = 0.f; }
#pragma unroll
  for (int r = 0; r < 16; ++r) {
    float th = acc[r] * invdt;                   // revolutions, |th| << 1
    float c1 = __builtin_amdgcn_cosf(th);        // v_cos_f32: cos(2*pi*th)
    float s1 = __builtin_amdgcn_sinf(th);        // v_sin_f32: sin(2*pi*th)
    float twoc = 2.f * c1;
    float ckm1 = 1.f, skm1 = 0.f;
    float ck = c1, sk = s1;
    cs[0] += c1;
    ss[0] += s1;
#pragma unroll
    for (int k = 2; k < NK; ++k) {
      float cn = fmaf(twoc, ck, -ckm1);
      float sn = fmaf(twoc, sk, -skm1);
      cs[k - 1] += cn;
      ss[k - 1] += sn;
      ckm1 = ck; skm1 = sk; ck = cn; sk = sn;
    }
  }

  // ---- combine the two b-halves (lane L and L^32 share the same p col) ----
#pragma unroll
  for (int k = 0; k < NK - 1; ++k) {
    cs[k] += __shfl_xor(cs[k], 32, 64);
    ss[k] += __shfl_xor(ss[k], 32, 64);
  }

  // ---- planes: cos[16][2 mt][64 p], sin @ +2048 ----
  if (lane < 32) {
    int p = nt * 32 + l31;
#pragma unroll
    for (int k = 0; k < NK - 1; ++k) {
      planes[k * 128 + mt * 64 + p]        = cs[k];
      planes[2048 + k * 128 + mt * 64 + p] = ss[k];
    }
  }
  __syncthreads();                               // (3) planes ready

  // ---- per-(k,p) error + weight dot ----
  float part = 0.f;
#pragma unroll
  for (int r = 0; r < 4; ++r) {
    int e  = tid + r * 256;                      // 0..1023
    int k1 = e >> 6;
    int pl = e & 63;
    float C = planes[k1 * 128 + pl] + planes[k1 * 128 + 64 + pl];
    float S = planes[2048 + k1 * 128 + pl] + planes[2048 + k1 * 128 + 64 + pl];
    float cm  = C * (1.f / 64.f);
    float sm_ = S * (1.f / 64.f);
    float tk  = (float)(k1 + 1) * DT;
    float phi = __expf(-0.5f * tk * tk);
    float wk  = ((k1 == NK - 2) ? DT : 2.f * DT) * phi;   // k=16 endpoint
    float dc  = cm - phi;
    part = fmaf(wk, fmaf(dc, dc, sm_ * sm_), part);
  }
  part *= (1.f / 512.f);                         // * B / (T*P)

  // ---- block reduce -> one atomic per block ----
#pragma unroll
  for (int off = 32; off > 0; off >>= 1)
    part += __shfl_down(part, off, 64);
  if (lane == 0) parts[wv] = part;               // disjoint region: no hazard
  __syncthreads();                               // (4) partials ready
  if (tid == 0)
    atomicAdd(out, parts[0] + parts[1] + parts[2] + parts[3]);
}

// ---------------------------------------------------------------------------
extern "C" void kernel_launch(void* const* d_in, const int* in_sizes, int n_in,
                              void* d_out, int out_size, void* d_ws, size_t ws_size,
                              hipStream_t stream) {
  const float* proj = (const float*)d_in[0];     // (32,64,256) fp32
  const float* A    = (const float*)d_in[1];     // (256,1024) fp32
  float* out        = (float*)d_out;             // 1 fp32 scalar

  hipMemsetAsync(out, 0, sizeof(float), stream); // d_out poisoned each call
  sig_fused_kernel<<<dim3(16, 32), dim3(256), 0, stream>>>(proj, A, out);
}